// Round 1
// baseline (1220.414 us; speedup 1.0000x reference)
//
#include <hip/hip_runtime.h>
#include <cmath>

#define B_ 2
#define S_ 2048
#define H_ 16
#define D_ 64
#define DM 1024

// ---------------------------------------------------------------------------
// GEMM1: qkv = x @ Wqkv + bqkv ; scatter output to [3][B][H][S][D]
// ---------------------------------------------------------------------------
__global__ __launch_bounds__(256) void relattn_gemm_qkv(
    const float* __restrict__ A,    // [B*S, DM]
    const float* __restrict__ W,    // [DM, 3*DM]
    const float* __restrict__ bias, // [3*DM]
    float* __restrict__ qkv)        // [3][B][H][S][D]
{
    __shared__ float As[16][72];   // transposed: As[k][row]
    __shared__ float Bs[16][72];   // Bs[k][col]
    const int tid = threadIdx.x;
    const int row0 = blockIdx.y * 64;
    const int col0 = blockIdx.x * 64;
    const int ty = tid >> 4, tx = tid & 15;
    const int lr = tid >> 2, lk4 = (tid & 3) * 4;     // A-load mapping
    const int lkB = tid >> 4, lc4 = (tid & 15) * 4;   // B-load mapping

    float acc[4][4];
#pragma unroll
    for (int i = 0; i < 4; ++i)
#pragma unroll
        for (int j = 0; j < 4; ++j) acc[i][j] = 0.f;

    for (int k0 = 0; k0 < DM; k0 += 16) {
        float4 a4 = *(const float4*)&A[(size_t)(row0 + lr) * DM + k0 + lk4];
        float4 b4 = *(const float4*)&W[(size_t)(k0 + lkB) * (3 * DM) + col0 + lc4];
        As[lk4 + 0][lr] = a4.x;
        As[lk4 + 1][lr] = a4.y;
        As[lk4 + 2][lr] = a4.z;
        As[lk4 + 3][lr] = a4.w;
        *(float4*)&Bs[lkB][lc4] = b4;
        __syncthreads();
#pragma unroll
        for (int k = 0; k < 16; ++k) {
            float4 av = *(const float4*)&As[k][ty * 4];
            float4 bv = *(const float4*)&Bs[k][tx * 4];
            float a_[4] = {av.x, av.y, av.z, av.w};
            float b_[4] = {bv.x, bv.y, bv.z, bv.w};
#pragma unroll
            for (int i = 0; i < 4; ++i)
#pragma unroll
                for (int j = 0; j < 4; ++j)
                    acc[i][j] = fmaf(a_[i], b_[j], acc[i][j]);
        }
        __syncthreads();
    }

    const int t = col0 >> 10;
    const int h = (col0 >> 6) & (H_ - 1);
    const int dcol = tx * 4;
#pragma unroll
    for (int i = 0; i < 4; ++i) {
        int row = row0 + ty * 4 + i;
        int bb = row >> 11;
        int ss = row & (S_ - 1);
        float4 o;
        o.x = acc[i][0] + bias[col0 + dcol + 0];
        o.y = acc[i][1] + bias[col0 + dcol + 1];
        o.z = acc[i][2] + bias[col0 + dcol + 2];
        o.w = acc[i][3] + bias[col0 + dcol + 3];
        size_t dst = ((((size_t)t * B_ + bb) * H_ + h) * S_ + ss) * D_ + dcol;
        *(float4*)&qkv[dst] = o;
    }
}

// ---------------------------------------------------------------------------
// GEMM2: out = attn @ Wout + bout  (row-major [B*S, DM])
// ---------------------------------------------------------------------------
__global__ __launch_bounds__(256) void relattn_gemm_out(
    const float* __restrict__ A,    // [B*S, DM]
    const float* __restrict__ W,    // [DM, DM]
    const float* __restrict__ bias, // [DM]
    float* __restrict__ out)        // [B*S, DM]
{
    __shared__ float As[16][72];
    __shared__ float Bs[16][72];
    const int tid = threadIdx.x;
    const int row0 = blockIdx.y * 64;
    const int col0 = blockIdx.x * 64;
    const int ty = tid >> 4, tx = tid & 15;
    const int lr = tid >> 2, lk4 = (tid & 3) * 4;
    const int lkB = tid >> 4, lc4 = (tid & 15) * 4;

    float acc[4][4];
#pragma unroll
    for (int i = 0; i < 4; ++i)
#pragma unroll
        for (int j = 0; j < 4; ++j) acc[i][j] = 0.f;

    for (int k0 = 0; k0 < DM; k0 += 16) {
        float4 a4 = *(const float4*)&A[(size_t)(row0 + lr) * DM + k0 + lk4];
        float4 b4 = *(const float4*)&W[(size_t)(k0 + lkB) * DM + col0 + lc4];
        As[lk4 + 0][lr] = a4.x;
        As[lk4 + 1][lr] = a4.y;
        As[lk4 + 2][lr] = a4.z;
        As[lk4 + 3][lr] = a4.w;
        *(float4*)&Bs[lkB][lc4] = b4;
        __syncthreads();
#pragma unroll
        for (int k = 0; k < 16; ++k) {
            float4 av = *(const float4*)&As[k][ty * 4];
            float4 bv = *(const float4*)&Bs[k][tx * 4];
            float a_[4] = {av.x, av.y, av.z, av.w};
            float b_[4] = {bv.x, bv.y, bv.z, bv.w};
#pragma unroll
            for (int i = 0; i < 4; ++i)
#pragma unroll
                for (int j = 0; j < 4; ++j)
                    acc[i][j] = fmaf(a_[i], b_[j], acc[i][j]);
        }
        __syncthreads();
    }

    const int dcol = tx * 4;
#pragma unroll
    for (int i = 0; i < 4; ++i) {
        int row = row0 + ty * 4 + i;
        float4 o;
        o.x = acc[i][0] + bias[col0 + dcol + 0];
        o.y = acc[i][1] + bias[col0 + dcol + 1];
        o.z = acc[i][2] + bias[col0 + dcol + 2];
        o.w = acc[i][3] + bias[col0 + dcol + 3];
        *(float4*)&out[(size_t)row * DM + col0 + dcol] = o;
    }
}

// ---------------------------------------------------------------------------
// Flash attention with relative position bias.
// Block = (qt, b*h): 64 q-rows. 256 threads: rgrp=tid>>4 (4 rows), cgrp=tid&15.
// LDS tiles 64x64 fp32, XOR quad-swizzle on row-varying reads.
// ---------------------------------------------------------------------------
__global__ __launch_bounds__(256) void relattn_attn(
    const float* __restrict__ qkv,  // [3][B][H][S][D]
    const float* __restrict__ relb, // [2*MAX_LEN-1] = [4095]
    float* __restrict__ out)        // [B][S][H*D]
{
    __shared__ float Qs[64][64];
    __shared__ float Ks[64][64];
    __shared__ float Vs[64][64];
    __shared__ float Ps[64][64];

    const int tid = threadIdx.x;
    const int qt = blockIdx.x;   // 0..31
    const int bh = blockIdx.y;   // 0..31
    const int b = bh >> 4, h = bh & (H_ - 1);
    const size_t plane = (size_t)S_ * D_;
    const float* qb = qkv + ((size_t)(b * H_ + h)) * plane;
    const float* kb = qkv + ((size_t)((B_ + b) * H_ + h)) * plane;
    const float* vb = qkv + ((size_t)((2 * B_ + b) * H_ + h)) * plane;

    const int rgrp = tid >> 4, cgrp = tid & 15;
    const int r0 = rgrp * 4, c0 = cgrp * 4;
    const float scale = 0.125f;  // 1/sqrt(64)

    // stage Q (swizzled: quad d4 of row r stored at quad (d4 ^ (r>>2)))
#pragma unroll
    for (int it = 0; it < 4; ++it) {
        int idx = tid + it * 256;
        int r = idx >> 4, d4 = idx & 15;
        float4 q4 = *(const float4*)&qb[(size_t)(qt * 64 + r) * D_ + d4 * 4];
        *(float4*)&Qs[r][4 * (d4 ^ ((r >> 2) & 15))] = q4;
    }

    float m_[4], l_[4], O[4][4];
#pragma unroll
    for (int i = 0; i < 4; ++i) {
        m_[i] = -INFINITY;
        l_[i] = 0.f;
#pragma unroll
        for (int j = 0; j < 4; ++j) O[i][j] = 0.f;
    }

    for (int kt = 0; kt < S_ / 64; ++kt) {
        __syncthreads();  // previous PV reads of Ks/Vs/Ps done
        // stage K (swizzled) and V (plain)
#pragma unroll
        for (int it = 0; it < 4; ++it) {
            int idx = tid + it * 256;
            int c = idx >> 4, d4 = idx & 15;
            float4 k4 = *(const float4*)&kb[(size_t)(kt * 64 + c) * D_ + d4 * 4];
            *(float4*)&Ks[c][4 * (d4 ^ ((c >> 2) & 15))] = k4;
            float4 v4 = *(const float4*)&vb[(size_t)(kt * 64 + c) * D_ + d4 * 4];
            *(float4*)&Vs[c][d4 * 4] = v4;
        }
        __syncthreads();

        // ---- QK^T : sc[i][j] = q[r0+i] . k[c0+j]
        float sc[4][4];
#pragma unroll
        for (int i = 0; i < 4; ++i)
#pragma unroll
            for (int j = 0; j < 4; ++j) sc[i][j] = 0.f;

#pragma unroll
        for (int dq = 0; dq < 16; ++dq) {
            float4 q4[4], k4[4];
#pragma unroll
            for (int i = 0; i < 4; ++i)
                q4[i] = *(const float4*)&Qs[r0 + i][4 * (dq ^ rgrp)];
#pragma unroll
            for (int j = 0; j < 4; ++j)
                k4[j] = *(const float4*)&Ks[c0 + j][4 * (dq ^ cgrp)];
#pragma unroll
            for (int i = 0; i < 4; ++i)
#pragma unroll
                for (int j = 0; j < 4; ++j) {
                    sc[i][j] = fmaf(q4[i].x, k4[j].x, sc[i][j]);
                    sc[i][j] = fmaf(q4[i].y, k4[j].y, sc[i][j]);
                    sc[i][j] = fmaf(q4[i].z, k4[j].z, sc[i][j]);
                    sc[i][j] = fmaf(q4[i].w, k4[j].w, sc[i][j]);
                }
        }

        // ---- scale + relative position bias (depends only on i-j per tile)
        float bias7[7];
        {
            int base0 = (qt - kt) * 64 + r0 - c0 + 2047;
#pragma unroll
            for (int dd = 0; dd < 7; ++dd) {
                int idx = base0 + dd - 3;
                idx = idx < 0 ? 0 : (idx > 4094 ? 4094 : idx);
                bias7[dd] = relb[idx];
            }
        }
#pragma unroll
        for (int i = 0; i < 4; ++i)
#pragma unroll
            for (int j = 0; j < 4; ++j)
                sc[i][j] = sc[i][j] * scale + bias7[i - j + 3];

        // ---- online softmax (row group = 16 consecutive lanes)
#pragma unroll
        for (int i = 0; i < 4; ++i) {
            float tmax = fmaxf(fmaxf(sc[i][0], sc[i][1]), fmaxf(sc[i][2], sc[i][3]));
#pragma unroll
            for (int off = 1; off < 16; off <<= 1)
                tmax = fmaxf(tmax, __shfl_xor(tmax, off, 16));
            float nm = fmaxf(m_[i], tmax);
            float al = expf(m_[i] - nm);
            float pr[4];
            float psum = 0.f;
#pragma unroll
            for (int j = 0; j < 4; ++j) {
                pr[j] = expf(sc[i][j] - nm);
                psum += pr[j];
            }
#pragma unroll
            for (int off = 1; off < 16; off <<= 1)
                psum += __shfl_xor(psum, off, 16);
            l_[i] = l_[i] * al + psum;
            m_[i] = nm;
#pragma unroll
            for (int j = 0; j < 4; ++j) O[i][j] *= al;
            *(float4*)&Ps[r0 + i][4 * (cgrp ^ rgrp)] =
                make_float4(pr[0], pr[1], pr[2], pr[3]);
        }
        __syncthreads();

        // ---- PV : O[i][j] += sum_k P[r0+i][k] * V[k][c0+j]
#pragma unroll
        for (int kq = 0; kq < 16; ++kq) {
            float4 p4[4];
            float p_[4][4];
#pragma unroll
            for (int i = 0; i < 4; ++i) {
                p4[i] = *(const float4*)&Ps[r0 + i][4 * (kq ^ rgrp)];
                p_[i][0] = p4[i].x; p_[i][1] = p4[i].y;
                p_[i][2] = p4[i].z; p_[i][3] = p4[i].w;
            }
#pragma unroll
            for (int kk = 0; kk < 4; ++kk) {
                float4 v4 = *(const float4*)&Vs[4 * kq + kk][c0];
#pragma unroll
                for (int i = 0; i < 4; ++i) {
                    O[i][0] = fmaf(p_[i][kk], v4.x, O[i][0]);
                    O[i][1] = fmaf(p_[i][kk], v4.y, O[i][1]);
                    O[i][2] = fmaf(p_[i][kk], v4.z, O[i][2]);
                    O[i][3] = fmaf(p_[i][kk], v4.w, O[i][3]);
                }
            }
        }
    }

    // ---- finalize: divide by l, write [B][S][H*D]
#pragma unroll
    for (int i = 0; i < 4; ++i) {
        float inv = 1.0f / l_[i];
        float4 o = make_float4(O[i][0] * inv, O[i][1] * inv,
                               O[i][2] * inv, O[i][3] * inv);
        size_t dst = ((size_t)b * S_ + (size_t)qt * 64 + r0 + i) * DM + h * D_ + c0;
        *(float4*)&out[dst] = o;
    }
}

// ---------------------------------------------------------------------------
extern "C" void kernel_launch(void* const* d_in, const int* in_sizes, int n_in,
                              void* d_out, int out_size, void* d_ws, size_t ws_size,
                              hipStream_t stream) {
    const float* x     = (const float*)d_in[0];
    const float* Wqkv  = (const float*)d_in[1];
    const float* bqkv  = (const float*)d_in[2];
    const float* Wout  = (const float*)d_in[3];
    const float* bout  = (const float*)d_in[4];
    const float* relb  = (const float*)d_in[5];
    float* out = (float*)d_out;

    float* qkv  = (float*)d_ws;                               // 3*B*H*S*D floats
    float* attn = qkv + (size_t)3 * B_ * H_ * S_ * D_;        // B*S*DM floats

    dim3 g1(3 * DM / 64, B_ * S_ / 64);   // (48, 64)
    relattn_gemm_qkv<<<g1, 256, 0, stream>>>(x, Wqkv, bqkv, qkv);

    dim3 g2(S_ / 64, B_ * H_);            // (32, 32)
    relattn_attn<<<g2, 256, 0, stream>>>(qkv, relb, attn);

    dim3 g3(DM / 64, B_ * S_ / 64);       // (16, 64)
    relattn_gemm_out<<<g3, 256, 0, stream>>>(attn, Wout, bout, out);
}

// Round 2
// 238.779 us; speedup vs baseline: 5.1111x; 5.1111x over previous
//
#include <hip/hip_runtime.h>
#include <cmath>

#define B_ 2
#define S_ 2048
#define H_ 16
#define D_ 64
#define DM 1024

typedef unsigned short u16;
using short8 = __attribute__((ext_vector_type(8))) short;
using f32x4  = __attribute__((ext_vector_type(4))) float;

__device__ __forceinline__ u16 f32_to_bf16(float f) {
    unsigned int u = __float_as_uint(f);
    u += 0x7fffu + ((u >> 16) & 1u);   // round-to-nearest-even
    return (u16)(u >> 16);
}

__device__ __forceinline__ void gl_lds16(const void* src, void* dst) {
    __builtin_amdgcn_global_load_lds(
        (const __attribute__((address_space(1))) unsigned int*)src,
        (__attribute__((address_space(3))) unsigned int*)dst, 16, 0, 0);
}

// ---------------------------------------------------------------------------
// prep: x -> bf16 ; Wqkv -> bf16 transposed [3072][1024]; Wout -> bf16 T [1024][1024]
// ---------------------------------------------------------------------------
__global__ __launch_bounds__(256) void relattn_prep(
    const float* __restrict__ x, const float* __restrict__ Wqkv,
    const float* __restrict__ Wout,
    u16* __restrict__ xb, u16* __restrict__ WqkvT, u16* __restrict__ WoutT)
{
    __shared__ float T[64][65];
    const int tid = threadIdx.x;
    int blk = blockIdx.x;
    if (blk < 2048) {                       // convert x: 8 elems/thread
        size_t base = ((size_t)blk * 256 + tid) * 8;
        float4 v0 = *(const float4*)(x + base);
        float4 v1 = *(const float4*)(x + base + 4);
        ushort4 p0 = make_ushort4(f32_to_bf16(v0.x), f32_to_bf16(v0.y),
                                  f32_to_bf16(v0.z), f32_to_bf16(v0.w));
        ushort4 p1 = make_ushort4(f32_to_bf16(v1.x), f32_to_bf16(v1.y),
                                  f32_to_bf16(v1.z), f32_to_bf16(v1.w));
        *(ushort4*)(xb + base) = p0;
        *(ushort4*)(xb + base + 4) = p1;
        return;
    }
    int id = blk - 2048;
    const float* in; u16* outp; int R, C;
    if (id < 768) { in = Wqkv; outp = WqkvT; R = 1024; C = 3072; }
    else          { id -= 768; in = Wout;  outp = WoutT; R = 1024; C = 1024; }
    const int tpr = C >> 6;
    const int r0 = (id / tpr) << 6, c0 = (id % tpr) << 6;
#pragma unroll
    for (int it = 0; it < 4; ++it) {
        int e = tid + it * 256;
        int row = e >> 4, c4 = (e & 15) << 2;
        float4 v = *(const float4*)(in + (size_t)(r0 + row) * C + c0 + c4);
        T[row][c4 + 0] = v.x; T[row][c4 + 1] = v.y;
        T[row][c4 + 2] = v.z; T[row][c4 + 3] = v.w;
    }
    __syncthreads();
#pragma unroll
    for (int it = 0; it < 4; ++it) {
        int e = tid + it * 256;
        int crow = e >> 4, r4 = (e & 15) << 2;
        ushort4 pk = make_ushort4(f32_to_bf16(T[r4 + 0][crow]), f32_to_bf16(T[r4 + 1][crow]),
                                  f32_to_bf16(T[r4 + 2][crow]), f32_to_bf16(T[r4 + 3][crow]));
        *(ushort4*)(outp + (size_t)(c0 + crow) * R + r0 + r4) = pk;
    }
}

// ---------------------------------------------------------------------------
// GEMM1: xb[4096,1024] @ WqkvT[3072,1024]^T + bqkv
//   -> q,k planes [2][B][H][S][D] bf16 ; v transposed -> Vt [B][H][D][S] bf16
// 128x128 tile, BK=64, 4 waves, MFMA 16x16x32 bf16, global_load_lds staging
// with pre-swizzled source + XOR-swizzled ds_read_b128.
// ---------------------------------------------------------------------------
__global__ __launch_bounds__(256) void relattn_gemm_qkv(
    const u16* __restrict__ A, const u16* __restrict__ Bm,
    const float* __restrict__ bias, u16* __restrict__ qk, u16* __restrict__ Vt)
{
    __shared__ alignas(16) unsigned char AsB[16384];
    __shared__ alignas(16) unsigned char BsB[16384];
    const int tid = threadIdx.x;
    const int w = tid >> 6, l = tid & 63, ln = l & 15, hi = l >> 4;
    const int wr = w >> 1, wc = w & 1;
    const int row0 = blockIdx.y * 128, col0 = blockIdx.x * 128;
    const char* Ab = (const char*)A;
    const char* Bb = (const char*)Bm;

    f32x4 acc[4][4] = {};
    for (int step = 0; step < 16; ++step) {
        __syncthreads();
#pragma unroll
        for (int it = 0; it < 4; ++it) {
            int dsto = it * 4096 + w * 1024;
            int o = dsto + l * 16;
            int row = o >> 7;
            int swz = (o & 127) ^ ((row & 7) << 4);
            gl_lds16(Ab + (size_t)(row0 + row) * 2048 + step * 128 + swz, AsB + dsto);
            gl_lds16(Bb + (size_t)(col0 + row) * 2048 + step * 128 + swz, BsB + dsto);
        }
        __syncthreads();
#pragma unroll
        for (int kk = 0; kk < 2; ++kk) {
            short8 a[4], b[4];
            const int kb = hi * 16 + kk * 64;
#pragma unroll
            for (int m = 0; m < 4; ++m) {
                int row = wr * 64 + m * 16 + ln;
                a[m] = *(const short8*)(AsB + row * 128 + (kb ^ ((row & 7) << 4)));
            }
#pragma unroll
            for (int n = 0; n < 4; ++n) {
                int row = wc * 64 + n * 16 + ln;
                b[n] = *(const short8*)(BsB + row * 128 + (kb ^ ((row & 7) << 4)));
            }
#pragma unroll
            for (int m = 0; m < 4; ++m)
#pragma unroll
                for (int n = 0; n < 4; ++n)
                    acc[m][n] = __builtin_amdgcn_mfma_f32_16x16x32_bf16(a[m], b[n], acc[m][n], 0, 0, 0);
        }
    }

    const int t = col0 >> 10;                 // 0=q,1=k,2=v (constant per block)
    const int bb = row0 >> 11;
    if (t < 2) {
#pragma unroll
        for (int n = 0; n < 4; ++n) {
            int c = col0 + wc * 64 + n * 16 + ln;
            int h = (c >> 6) & 15, d = c & 63;
            float bv = bias[c];
            u16* plane = qk + (size_t)((t * B_ + bb) * H_ + h) * S_ * D_;
#pragma unroll
            for (int m = 0; m < 4; ++m)
#pragma unroll
                for (int r = 0; r < 4; ++r) {
                    int s = (row0 + wr * 64 + m * 16 + hi * 4 + r) & (S_ - 1);
                    plane[(size_t)s * D_ + d] = f32_to_bf16(acc[m][n][r] + bv);
                }
        }
    } else {
#pragma unroll
        for (int n = 0; n < 4; ++n) {
            int c = col0 + wc * 64 + n * 16 + ln;
            int h = (c >> 6) & 15, d = c & 63;
            float bv = bias[c];
            u16* vrow = Vt + (size_t)((bb * H_ + h) * D_ + d) * S_;
#pragma unroll
            for (int m = 0; m < 4; ++m) {
                int s = (row0 + wr * 64 + m * 16 + hi * 4) & (S_ - 1);
                ushort4 pk = make_ushort4(f32_to_bf16(acc[m][n][0] + bv),
                                          f32_to_bf16(acc[m][n][1] + bv),
                                          f32_to_bf16(acc[m][n][2] + bv),
                                          f32_to_bf16(acc[m][n][3] + bv));
                *(ushort4*)(vrow + s) = pk;
            }
        }
    }
}

// ---------------------------------------------------------------------------
// Flash attention, bf16 MFMA. Block: 4 waves x 32 q-rows (QBLK=128), KVBLK=64.
// K tile + V^T tile staged in LDS (swizzled); P via per-wave swizzled LDS.
// ---------------------------------------------------------------------------
__global__ __launch_bounds__(256) void relattn_attn(
    const u16* __restrict__ qk, const u16* __restrict__ Vt,
    const float* __restrict__ relb, u16* __restrict__ aout)
{
    __shared__ alignas(16) unsigned char KsB[8192];
    __shared__ alignas(16) unsigned char VtsB[8192];
    __shared__ alignas(16) unsigned char PsB[16384];
    const int tid = threadIdx.x;
    const int w = tid >> 6, l = tid & 63, ln = l & 15, hi = l >> 4;
    const int qt = blockIdx.x, bh = blockIdx.y;
    const int bb = bh >> 4;
    const char* qpl = (const char*)(qk + (size_t)bh * (S_ * D_));
    const char* kpl = (const char*)(qk + (size_t)(B_ * H_ + bh) * (S_ * D_));
    const char* vpl = (const char*)(Vt + (size_t)bh * (D_ * S_));
    unsigned char* PsW = PsB + w * 4096;

    short8 qf[2][2];
#pragma unroll
    for (int m = 0; m < 2; ++m)
#pragma unroll
        for (int kk = 0; kk < 2; ++kk) {
            int q = qt * 128 + w * 32 + m * 16 + ln;
            qf[m][kk] = *(const short8*)(qpl + (size_t)q * 128 + hi * 16 + kk * 64);
        }

    f32x4 O[2][4] = {};
    float mst[2][4], lst[2][4];
#pragma unroll
    for (int m = 0; m < 2; ++m)
#pragma unroll
        for (int r = 0; r < 4; ++r) { mst[m][r] = -1e30f; lst[m][r] = 0.f; }

    const int qrow_l = qt * 128 + w * 32 + hi * 4;

    for (int kt = 0; kt < S_ / 64; ++kt) {
        __syncthreads();
#pragma unroll
        for (int it = 0; it < 2; ++it) {
            int dsto = it * 4096 + w * 1024;
            int o = dsto + l * 16;
            int row = o >> 7;
            int swz = (o & 127) ^ ((row & 7) << 4);
            gl_lds16(kpl + (size_t)(kt * 64 + row) * 128 + swz, KsB + dsto);
            gl_lds16(vpl + (size_t)row * (S_ * 2) + kt * 128 + swz, VtsB + dsto);
        }
        __syncthreads();

        // ---- S = Q K^T
        f32x4 sc[2][4] = {};
#pragma unroll
        for (int kk = 0; kk < 2; ++kk) {
            short8 kf[4];
            const int kb = hi * 16 + kk * 64;
#pragma unroll
            for (int n = 0; n < 4; ++n) {
                int row = n * 16 + ln;
                kf[n] = *(const short8*)(KsB + row * 128 + (kb ^ ((row & 7) << 4)));
            }
#pragma unroll
            for (int m = 0; m < 2; ++m)
#pragma unroll
                for (int n = 0; n < 4; ++n)
                    sc[m][n] = __builtin_amdgcn_mfma_f32_16x16x32_bf16(qf[m][kk], kf[n], sc[m][n], 0, 0, 0);
        }

        // ---- scale + relative bias (idx always in [0,4094])
        const int idx0 = qrow_l - kt * 64 - ln + 2047;
#pragma unroll
        for (int m = 0; m < 2; ++m)
#pragma unroll
            for (int n = 0; n < 4; ++n)
#pragma unroll
                for (int r = 0; r < 4; ++r)
                    sc[m][n][r] = sc[m][n][r] * 0.125f + relb[idx0 + m * 16 + r - n * 16];

        // ---- online softmax (row group = 16 lanes)
#pragma unroll
        for (int m = 0; m < 2; ++m) {
            float al[4];
#pragma unroll
            for (int r = 0; r < 4; ++r) {
                float tm = fmaxf(fmaxf(sc[m][0][r], sc[m][1][r]), fmaxf(sc[m][2][r], sc[m][3][r]));
                tm = fmaxf(tm, __shfl_xor(tm, 1, 16));
                tm = fmaxf(tm, __shfl_xor(tm, 2, 16));
                tm = fmaxf(tm, __shfl_xor(tm, 4, 16));
                tm = fmaxf(tm, __shfl_xor(tm, 8, 16));
                float nm = fmaxf(mst[m][r], tm);
                al[r] = __expf(mst[m][r] - nm);
                mst[m][r] = nm;
                float ps = 0.f;
#pragma unroll
                for (int n = 0; n < 4; ++n) {
                    float p = __expf(sc[m][n][r] - nm);
                    sc[m][n][r] = p;
                    ps += p;
                }
                ps += __shfl_xor(ps, 1, 16);
                ps += __shfl_xor(ps, 2, 16);
                ps += __shfl_xor(ps, 4, 16);
                ps += __shfl_xor(ps, 8, 16);
                lst[m][r] = lst[m][r] * al[r] + ps;
            }
#pragma unroll
            for (int nd = 0; nd < 4; ++nd) {
                O[m][nd][0] *= al[0]; O[m][nd][1] *= al[1];
                O[m][nd][2] *= al[2]; O[m][nd][3] *= al[3];
            }
#pragma unroll
            for (int r = 0; r < 4; ++r) {
                int row = m * 16 + hi * 4 + r;
                int sw = (row & 7) << 4;
#pragma unroll
                for (int n = 0; n < 4; ++n)
                    *(u16*)(PsW + row * 128 + ((n * 32 + ln * 2) ^ sw)) = f32_to_bf16(sc[m][n][r]);
            }
        }

        // ---- O += P V
#pragma unroll
        for (int kk = 0; kk < 2; ++kk) {
            short8 pf[2], vf[4];
            const int kb = hi * 16 + kk * 64;
#pragma unroll
            for (int m = 0; m < 2; ++m) {
                int row = m * 16 + ln;
                pf[m] = *(const short8*)(PsW + row * 128 + (kb ^ ((row & 7) << 4)));
            }
#pragma unroll
            for (int nd = 0; nd < 4; ++nd) {
                int row = nd * 16 + ln;
                vf[nd] = *(const short8*)(VtsB + row * 128 + (kb ^ ((row & 7) << 4)));
            }
#pragma unroll
            for (int m = 0; m < 2; ++m)
#pragma unroll
                for (int nd = 0; nd < 4; ++nd)
                    O[m][nd] = __builtin_amdgcn_mfma_f32_16x16x32_bf16(pf[m], vf[nd], O[m][nd], 0, 0, 0);
        }
    }

    // ---- epilogue: normalize, write bf16 [B*S][DM]
#pragma unroll
    for (int m = 0; m < 2; ++m) {
        float inv[4];
#pragma unroll
        for (int r = 0; r < 4; ++r) inv[r] = 1.0f / lst[m][r];
#pragma unroll
        for (int nd = 0; nd < 4; ++nd)
#pragma unroll
            for (int r = 0; r < 4; ++r) {
                int q = qrow_l + m * 16 + r;
                int col = (bh & 15) * 64 + nd * 16 + ln;
                aout[(size_t)(bb * S_ + q) * DM + col] = f32_to_bf16(O[m][nd][r] * inv[r]);
            }
    }
}

// ---------------------------------------------------------------------------
// GEMM2: aout[4096,1024](bf16) @ WoutT[1024,1024]^T + bout -> out f32
// ---------------------------------------------------------------------------
__global__ __launch_bounds__(256) void relattn_gemm_out(
    const u16* __restrict__ A, const u16* __restrict__ Bm,
    const float* __restrict__ bias, float* __restrict__ out)
{
    __shared__ alignas(16) unsigned char AsB[16384];
    __shared__ alignas(16) unsigned char BsB[16384];
    const int tid = threadIdx.x;
    const int w = tid >> 6, l = tid & 63, ln = l & 15, hi = l >> 4;
    const int wr = w >> 1, wc = w & 1;
    const int row0 = blockIdx.y * 128, col0 = blockIdx.x * 128;
    const char* Ab = (const char*)A;
    const char* Bb = (const char*)Bm;

    f32x4 acc[4][4] = {};
    for (int step = 0; step < 16; ++step) {
        __syncthreads();
#pragma unroll
        for (int it = 0; it < 4; ++it) {
            int dsto = it * 4096 + w * 1024;
            int o = dsto + l * 16;
            int row = o >> 7;
            int swz = (o & 127) ^ ((row & 7) << 4);
            gl_lds16(Ab + (size_t)(row0 + row) * 2048 + step * 128 + swz, AsB + dsto);
            gl_lds16(Bb + (size_t)(col0 + row) * 2048 + step * 128 + swz, BsB + dsto);
        }
        __syncthreads();
#pragma unroll
        for (int kk = 0; kk < 2; ++kk) {
            short8 a[4], b[4];
            const int kb = hi * 16 + kk * 64;
#pragma unroll
            for (int m = 0; m < 4; ++m) {
                int row = wr * 64 + m * 16 + ln;
                a[m] = *(const short8*)(AsB + row * 128 + (kb ^ ((row & 7) << 4)));
            }
#pragma unroll
            for (int n = 0; n < 4; ++n) {
                int row = wc * 64 + n * 16 + ln;
                b[n] = *(const short8*)(BsB + row * 128 + (kb ^ ((row & 7) << 4)));
            }
#pragma unroll
            for (int m = 0; m < 4; ++m)
#pragma unroll
                for (int n = 0; n < 4; ++n)
                    acc[m][n] = __builtin_amdgcn_mfma_f32_16x16x32_bf16(a[m], b[n], acc[m][n], 0, 0, 0);
        }
    }

#pragma unroll
    for (int n = 0; n < 4; ++n) {
        int c = col0 + wc * 64 + n * 16 + ln;
        float bv = bias[c];
#pragma unroll
        for (int m = 0; m < 4; ++m)
#pragma unroll
            for (int r = 0; r < 4; ++r) {
                int row = row0 + wr * 64 + m * 16 + hi * 4 + r;
                out[(size_t)row * DM + c] = acc[m][n][r] + bv;
            }
    }
}

// ---------------------------------------------------------------------------
extern "C" void kernel_launch(void* const* d_in, const int* in_sizes, int n_in,
                              void* d_out, int out_size, void* d_ws, size_t ws_size,
                              hipStream_t stream) {
    const float* x    = (const float*)d_in[0];
    const float* Wqkv = (const float*)d_in[1];
    const float* bqkv = (const float*)d_in[2];
    const float* Wout = (const float*)d_in[3];
    const float* bout = (const float*)d_in[4];
    const float* relb = (const float*)d_in[5];
    float* out = (float*)d_out;

    u16* ws    = (u16*)d_ws;
    u16* xb    = ws;                       // 4096*1024
    u16* WqkvT = xb + 4194304;             // 3072*1024
    u16* WoutT = WqkvT + 3145728;          // 1024*1024
    u16* qkpl  = WoutT + 1048576;          // [2][B][H][S][D] = 8388608
    u16* Vt    = qkpl + 8388608;           // [B][H][D][S]    = 4194304
    u16* aout  = Vt + 4194304;             // 4096*1024       = 4194304

    relattn_prep<<<3072, 256, 0, stream>>>(x, Wqkv, Wout, xb, WqkvT, WoutT);
    relattn_gemm_qkv<<<dim3(24, 32), 256, 0, stream>>>(xb, WqkvT, bqkv, qkpl, Vt);
    relattn_attn<<<dim3(16, 32), 256, 0, stream>>>(qkpl, Vt, relb, aout);
    relattn_gemm_out<<<dim3(8, 32), 256, 0, stream>>>(aout, WoutT, bout, out);
}

// Round 4
// 146.346 us; speedup vs baseline: 8.3392x; 1.6316x over previous
//
#include <hip/hip_runtime.h>
#include <cmath>

#define B_ 2
#define S_ 2048
#define H_ 16
#define D_ 64
#define DM 1024

typedef unsigned short u16;
using short8 = __attribute__((ext_vector_type(8))) short;
using f32x4  = __attribute__((ext_vector_type(4))) float;
using f32x16 = __attribute__((ext_vector_type(16))) float;
using i32x4  = __attribute__((ext_vector_type(4))) int;

__device__ __forceinline__ u16 f32_to_bf16(float f) {
    unsigned int u = __float_as_uint(f);
    u += 0x7fffu + ((u >> 16) & 1u);   // round-to-nearest-even
    return (u16)(u >> 16);
}

__device__ __forceinline__ float exp2_fast(float x) {
    float r;
    asm("v_exp_f32 %0, %1" : "=v"(r) : "v"(x));
    return r;
}

__device__ __forceinline__ int cvt_pk_bf16(float lo, float hi) {
    int r;
    asm("v_cvt_pk_bf16_f32 %0, %1, %2" : "=v"(r) : "v"(lo), "v"(hi));
    return r;
}

__device__ __forceinline__ void gl_lds16(const void* src, void* dst) {
    __builtin_amdgcn_global_load_lds(
        (const __attribute__((address_space(1))) unsigned int*)src,
        (__attribute__((address_space(3))) unsigned int*)dst, 16, 0, 0);
}

__device__ __forceinline__ f32x16 mfma32(short8 a, short8 b, f32x16 c) {
    return __builtin_amdgcn_mfma_f32_32x32x16_bf16(a, b, c, 0, 0, 0);
}

// ---------------------------------------------------------------------------
// prep: x -> bf16 ; Wqkv -> bf16 T [3072][1024]; Wout -> bf16 T [1024][1024];
//       relb -> relb2 = relb * log2(e)
// ---------------------------------------------------------------------------
__global__ __launch_bounds__(256) void relattn_prep(
    const float* __restrict__ x, const float* __restrict__ Wqkv,
    const float* __restrict__ Wout, const float* __restrict__ relb,
    u16* __restrict__ xb, u16* __restrict__ WqkvT, u16* __restrict__ WoutT,
    float* __restrict__ relb2)
{
    __shared__ float T[64][65];
    const int tid = threadIdx.x;
    int blk = blockIdx.x;
    if (blk >= 3072) {                      // scale bias table into log2 domain
        int i0 = ((blk - 3072) * 256 + tid) * 4;
#pragma unroll
        for (int j = 0; j < 4; ++j)
            if (i0 + j < 2 * 2048 - 1)
                relb2[i0 + j] = relb[i0 + j] * 1.44269504f;
        return;
    }
    if (blk < 2048) {                       // convert x: 8 elems/thread
        size_t base = ((size_t)blk * 256 + tid) * 8;
        float4 v0 = *(const float4*)(x + base);
        float4 v1 = *(const float4*)(x + base + 4);
        ushort4 p0 = make_ushort4(f32_to_bf16(v0.x), f32_to_bf16(v0.y),
                                  f32_to_bf16(v0.z), f32_to_bf16(v0.w));
        ushort4 p1 = make_ushort4(f32_to_bf16(v1.x), f32_to_bf16(v1.y),
                                  f32_to_bf16(v1.z), f32_to_bf16(v1.w));
        *(ushort4*)(xb + base) = p0;
        *(ushort4*)(xb + base + 4) = p1;
        return;
    }
    int id = blk - 2048;
    const float* in; u16* outp; int R, C;
    if (id < 768) { in = Wqkv; outp = WqkvT; R = 1024; C = 3072; }
    else          { id -= 768; in = Wout;  outp = WoutT; R = 1024; C = 1024; }
    const int tpr = C >> 6;
    const int r0 = (id / tpr) << 6, c0 = (id % tpr) << 6;
#pragma unroll
    for (int it = 0; it < 4; ++it) {
        int e = tid + it * 256;
        int row = e >> 4, c4 = (e & 15) << 2;
        float4 v = *(const float4*)(in + (size_t)(r0 + row) * C + c0 + c4);
        T[row][c4 + 0] = v.x; T[row][c4 + 1] = v.y;
        T[row][c4 + 2] = v.z; T[row][c4 + 3] = v.w;
    }
    __syncthreads();
#pragma unroll
    for (int it = 0; it < 4; ++it) {
        int e = tid + it * 256;
        int crow = e >> 4, r4 = (e & 15) << 2;
        ushort4 pk = make_ushort4(f32_to_bf16(T[r4 + 0][crow]), f32_to_bf16(T[r4 + 1][crow]),
                                  f32_to_bf16(T[r4 + 2][crow]), f32_to_bf16(T[r4 + 3][crow]));
        *(ushort4*)(outp + (size_t)(c0 + crow) * R + r0 + r4) = pk;
    }
}

// ---------------------------------------------------------------------------
// GEMM1: xb @ WqkvT^T + bqkv -> q,k planes [2][B][H][S][D]; v -> Vt [B][H][D][S]
// ---------------------------------------------------------------------------
__global__ __launch_bounds__(256) void relattn_gemm_qkv(
    const u16* __restrict__ A, const u16* __restrict__ Bm,
    const float* __restrict__ bias, u16* __restrict__ qk, u16* __restrict__ Vt)
{
    __shared__ alignas(16) unsigned char AsB[16384];
    __shared__ alignas(16) unsigned char BsB[16384];
    const int tid = threadIdx.x;
    const int w = tid >> 6, l = tid & 63, ln = l & 15, hi = l >> 4;
    const int wr = w >> 1, wc = w & 1;
    const int row0 = blockIdx.y * 128, col0 = blockIdx.x * 128;
    const char* Ab = (const char*)A;
    const char* Bb = (const char*)Bm;

    f32x4 acc[4][4] = {};
    for (int step = 0; step < 16; ++step) {
        __syncthreads();
#pragma unroll
        for (int it = 0; it < 4; ++it) {
            int dsto = it * 4096 + w * 1024;
            int o = dsto + l * 16;
            int row = o >> 7;
            int swz = (o & 127) ^ ((row & 7) << 4);
            gl_lds16(Ab + (size_t)(row0 + row) * 2048 + step * 128 + swz, AsB + dsto);
            gl_lds16(Bb + (size_t)(col0 + row) * 2048 + step * 128 + swz, BsB + dsto);
        }
        __syncthreads();
#pragma unroll
        for (int kk = 0; kk < 2; ++kk) {
            short8 a[4], b[4];
            const int kb = hi * 16 + kk * 64;
#pragma unroll
            for (int m = 0; m < 4; ++m) {
                int row = wr * 64 + m * 16 + ln;
                a[m] = *(const short8*)(AsB + row * 128 + (kb ^ ((row & 7) << 4)));
            }
#pragma unroll
            for (int n = 0; n < 4; ++n) {
                int row = wc * 64 + n * 16 + ln;
                b[n] = *(const short8*)(BsB + row * 128 + (kb ^ ((row & 7) << 4)));
            }
#pragma unroll
            for (int m = 0; m < 4; ++m)
#pragma unroll
                for (int n = 0; n < 4; ++n)
                    acc[m][n] = __builtin_amdgcn_mfma_f32_16x16x32_bf16(a[m], b[n], acc[m][n], 0, 0, 0);
        }
    }

    const int t = col0 >> 10;
    const int bb = row0 >> 11;
    if (t < 2) {
#pragma unroll
        for (int n = 0; n < 4; ++n) {
            int c = col0 + wc * 64 + n * 16 + ln;
            int h = (c >> 6) & 15, d = c & 63;
            float bv = bias[c];
            u16* plane = qk + (size_t)((t * B_ + bb) * H_ + h) * S_ * D_;
#pragma unroll
            for (int m = 0; m < 4; ++m)
#pragma unroll
                for (int r = 0; r < 4; ++r) {
                    int s = (row0 + wr * 64 + m * 16 + hi * 4 + r) & (S_ - 1);
                    plane[(size_t)s * D_ + d] = f32_to_bf16(acc[m][n][r] + bv);
                }
        }
    } else {
#pragma unroll
        for (int n = 0; n < 4; ++n) {
            int c = col0 + wc * 64 + n * 16 + ln;
            int h = (c >> 6) & 15, d = c & 63;
            float bv = bias[c];
            u16* vrow = Vt + (size_t)((bb * H_ + h) * D_ + d) * S_;
#pragma unroll
            for (int m = 0; m < 4; ++m) {
                int s = (row0 + wr * 64 + m * 16 + hi * 4) & (S_ - 1);
                ushort4 pk = make_ushort4(f32_to_bf16(acc[m][n][0] + bv),
                                          f32_to_bf16(acc[m][n][1] + bv),
                                          f32_to_bf16(acc[m][n][2] + bv),
                                          f32_to_bf16(acc[m][n][3] + bv));
                *(ushort4*)(vrow + s) = pk;
            }
        }
    }
}

// ---------------------------------------------------------------------------
// Flash attention, fully swapped (m214-style): S^T = K Q^T AND O^T = V^T P^T.
// 4 warps x 32 q-rows (QBLK=128), KVBLK=64. Lane owns q-row l&31 end-to-end:
// P-row in 32 f32 regs, in-register softmax (exp2 domain), alpha applies
// in-lane to O^T (col = q = l&31). P->B-frag via cvt_pk + shfl_xor(32).
// ---------------------------------------------------------------------------
__global__ __launch_bounds__(256) void relattn_attn(
    const u16* __restrict__ qk, const u16* __restrict__ Vt,
    const float* __restrict__ relb2, u16* __restrict__ aout)
{
    __shared__ alignas(16) unsigned char Lds[32768];   // 2 bufs x (K 8K + V 8K)
    const int tid = threadIdx.x;
    const int w = tid >> 6, l = tid & 63;
    const int l31 = l & 31, h2 = l >> 5;
    const int qt = blockIdx.x, bh = blockIdx.y;
    const int bb = bh >> 4;
    const char* qpl = (const char*)(qk + (size_t)bh * (S_ * D_));
    const char* kpl = (const char*)(qk + (size_t)(B_ * H_ + bh) * (S_ * D_));
    const char* vpl = (const char*)(Vt + (size_t)bh * (D_ * S_));

    const int q0 = qt * 128 + w * 32;
    const int qrow = q0 + l31;

    // Q fragments: B-operand of swapped QK^T; lane l: row qrow, k-half h2
    short8 qf[4];
#pragma unroll
    for (int kd = 0; kd < 4; ++kd)
        qf[kd] = *(const short8*)(qpl + (size_t)qrow * 128 + kd * 32 + h2 * 16);

    f32x16 O0 = {}, O1 = {};
    float mrun = -1e30f, lrun = 0.f;

    // ---- prologue stage kt=0 into buf 0
    {
#pragma unroll
        for (int it = 0; it < 2; ++it) {
            int dsto = it * 4096 + w * 1024;
            int o = dsto + l * 16;
            int row = o >> 7;
            int swz = (o & 127) ^ ((row & 7) << 4);
            gl_lds16(kpl + (size_t)row * 128 + swz, Lds + dsto);
            gl_lds16(vpl + (size_t)row * (S_ * 2) + swz, Lds + 8192 + dsto);
        }
    }
    __syncthreads();

    for (int kt = 0; kt < S_ / 64; ++kt) {
        const int buf = kt & 1;
        const unsigned char* KB = Lds + buf * 16384;
        const unsigned char* VB = KB + 8192;

        // ---- prefetch next tile into other buffer (overlaps with compute)
        if (kt < S_ / 64 - 1) {
#pragma unroll
            for (int it = 0; it < 2; ++it) {
                int dsto = it * 4096 + w * 1024;
                int o = dsto + l * 16;
                int row = o >> 7;
                int swz = (o & 127) ^ ((row & 7) << 4);
                unsigned char* db = Lds + (buf ^ 1) * 16384 + dsto;
                gl_lds16(kpl + (size_t)((kt + 1) * 64 + row) * 128 + swz, db);
                gl_lds16(vpl + (size_t)row * (S_ * 2) + (kt + 1) * 128 + swz, db + 8192);
            }
        }

        // ---- S^T = K Q^T : lane owns q-col qrow; regs span kv 0..63
        f32x16 s0 = {}, s1 = {};
#pragma unroll
        for (int kd = 0; kd < 4; ++kd) {
            int kbyte = kd * 32 + h2 * 16;
            int sw = (l31 & 7) << 4;
            short8 k0 = *(const short8*)(KB + l31 * 128 + (kbyte ^ sw));
            short8 k1 = *(const short8*)(KB + (32 + l31) * 128 + (kbyte ^ sw));
            s0 = mfma32(k0, qf[kd], s0);
            s1 = mfma32(k1, qf[kd], s1);
        }

        // ---- scale + relative bias (log2 domain); kv = kt*64+{0,32}+8*rq+j+4*h2
        const float SC2 = 0.125f * 1.44269504f;
        const float* bp = relb2 + (qrow - kt * 64 - 4 * h2 + 2047);
#pragma unroll
        for (int rq = 0; rq < 4; ++rq)
#pragma unroll
            for (int j = 0; j < 4; ++j) {
                s0[rq * 4 + j] = s0[rq * 4 + j] * SC2 + bp[-(8 * rq + j)];
                s1[rq * 4 + j] = s1[rq * 4 + j] * SC2 + bp[-(32 + 8 * rq + j)];
            }

        // ---- online softmax, in-lane + one cross-half combine
        float tm = -1e30f;
#pragma unroll
        for (int r = 0; r < 16; ++r) {
            tm = fmaxf(tm, s0[r]);
            tm = fmaxf(tm, s1[r]);
        }
        tm = fmaxf(tm, __shfl_xor(tm, 32));
        float nm = fmaxf(mrun, tm);
        float al = exp2_fast(mrun - nm);
        mrun = nm;
        float ps = 0.f;
#pragma unroll
        for (int r = 0; r < 16; ++r) { s0[r] = exp2_fast(s0[r] - nm); ps += s0[r]; }
#pragma unroll
        for (int r = 0; r < 16; ++r) { s1[r] = exp2_fast(s1[r] - nm); ps += s1[r]; }
        ps += __shfl_xor(ps, 32);
        lrun = lrun * al + ps;
#pragma unroll
        for (int r = 0; r < 16; ++r) { O0[r] *= al; O1[r] *= al; }

        // ---- P -> B-fragments (half-exchange) + swapped PV: O^T = V^T P^T
#pragma unroll
        for (int ts = 0; ts < 4; ++ts) {
            float p0, p1, p2, p3, p4, p5, p6, p7;
            if (ts == 0)      { p0=s0[0];  p1=s0[1];  p2=s0[2];  p3=s0[3];  p4=s0[4];  p5=s0[5];  p6=s0[6];  p7=s0[7]; }
            else if (ts == 1) { p0=s0[8];  p1=s0[9];  p2=s0[10]; p3=s0[11]; p4=s0[12]; p5=s0[13]; p6=s0[14]; p7=s0[15]; }
            else if (ts == 2) { p0=s1[0];  p1=s1[1];  p2=s1[2];  p3=s1[3];  p4=s1[4];  p5=s1[5];  p6=s1[6];  p7=s1[7]; }
            else              { p0=s1[8];  p1=s1[9];  p2=s1[10]; p3=s1[11]; p4=s1[12]; p5=s1[13]; p6=s1[14]; p7=s1[15]; }
            int c01 = cvt_pk_bf16(p0, p1), c23 = cvt_pk_bf16(p2, p3);
            int c45 = cvt_pk_bf16(p4, p5), c67 = cvt_pk_bf16(p6, p7);
            int px01 = __shfl_xor(c01, 32), px23 = __shfl_xor(c23, 32);
            int px45 = __shfl_xor(c45, 32), px67 = __shfl_xor(c67, 32);
            i32x4 pw;
            pw[0] = h2 ? px45 : c01;
            pw[1] = h2 ? px67 : c23;
            pw[2] = h2 ? c45 : px01;
            pw[3] = h2 ? c67 : px23;
            short8 pb = __builtin_bit_cast(short8, pw);
            int vbyte = ts * 32 + h2 * 16;
            int sw = (l31 & 7) << 4;
            short8 v0 = *(const short8*)(VB + l31 * 128 + (vbyte ^ sw));
            short8 v1 = *(const short8*)(VB + (32 + l31) * 128 + (vbyte ^ sw));
            O0 = mfma32(v0, pb, O0);   // D[d][q]: col = q = l31 -> alpha in-lane
            O1 = mfma32(v1, pb, O1);
        }
        __syncthreads();   // drains vmcnt (prefetch) + lgkm; next buf ready
    }

    // ---- epilogue: normalize, write bf16 [B*S][DM]; lane owns q-row qrow.
    // O0[r] -> d = (r&3)+8*(r>>2)+4*h2 ; O1[r] -> d+32. 4 consecutive d per group.
    float inv = 1.0f / lrun;
    u16* orow = aout + (size_t)(bb * S_ + qrow) * DM + (bh & 15) * 64 + 4 * h2;
#pragma unroll
    for (int g = 0; g < 4; ++g) {
        ushort4 w0 = make_ushort4(f32_to_bf16(O0[4 * g + 0] * inv), f32_to_bf16(O0[4 * g + 1] * inv),
                                  f32_to_bf16(O0[4 * g + 2] * inv), f32_to_bf16(O0[4 * g + 3] * inv));
        ushort4 w1 = make_ushort4(f32_to_bf16(O1[4 * g + 0] * inv), f32_to_bf16(O1[4 * g + 1] * inv),
                                  f32_to_bf16(O1[4 * g + 2] * inv), f32_to_bf16(O1[4 * g + 3] * inv));
        *(ushort4*)(orow + 8 * g) = w0;
        *(ushort4*)(orow + 32 + 8 * g) = w1;
    }
}

// ---------------------------------------------------------------------------
// GEMM2: aout[4096,1024](bf16) @ WoutT[1024,1024]^T + bout -> out f32
// ---------------------------------------------------------------------------
__global__ __launch_bounds__(256) void relattn_gemm_out(
    const u16* __restrict__ A, const u16* __restrict__ Bm,
    const float* __restrict__ bias, float* __restrict__ out)
{
    __shared__ alignas(16) unsigned char AsB[16384];
    __shared__ alignas(16) unsigned char BsB[16384];
    const int tid = threadIdx.x;
    const int w = tid >> 6, l = tid & 63, ln = l & 15, hi = l >> 4;
    const int wr = w >> 1, wc = w & 1;
    const int row0 = blockIdx.y * 128, col0 = blockIdx.x * 128;
    const char* Ab = (const char*)A;
    const char* Bb = (const char*)Bm;

    f32x4 acc[4][4] = {};
    for (int step = 0; step < 16; ++step) {
        __syncthreads();
#pragma unroll
        for (int it = 0; it < 4; ++it) {
            int dsto = it * 4096 + w * 1024;
            int o = dsto + l * 16;
            int row = o >> 7;
            int swz = (o & 127) ^ ((row & 7) << 4);
            gl_lds16(Ab + (size_t)(row0 + row) * 2048 + step * 128 + swz, AsB + dsto);
            gl_lds16(Bb + (size_t)(col0 + row) * 2048 + step * 128 + swz, BsB + dsto);
        }
        __syncthreads();
#pragma unroll
        for (int kk = 0; kk < 2; ++kk) {
            short8 a[4], b[4];
            const int kb = hi * 16 + kk * 64;
#pragma unroll
            for (int m = 0; m < 4; ++m) {
                int row = wr * 64 + m * 16 + ln;
                a[m] = *(const short8*)(AsB + row * 128 + (kb ^ ((row & 7) << 4)));
            }
#pragma unroll
            for (int n = 0; n < 4; ++n) {
                int row = wc * 64 + n * 16 + ln;
                b[n] = *(const short8*)(BsB + row * 128 + (kb ^ ((row & 7) << 4)));
            }
#pragma unroll
            for (int m = 0; m < 4; ++m)
#pragma unroll
                for (int n = 0; n < 4; ++n)
                    acc[m][n] = __builtin_amdgcn_mfma_f32_16x16x32_bf16(a[m], b[n], acc[m][n], 0, 0, 0);
        }
    }

#pragma unroll
    for (int n = 0; n < 4; ++n) {
        int c = col0 + wc * 64 + n * 16 + ln;
        float bv = bias[c];
#pragma unroll
        for (int m = 0; m < 4; ++m)
#pragma unroll
            for (int r = 0; r < 4; ++r) {
                int row = row0 + wr * 64 + m * 16 + hi * 4 + r;
                out[(size_t)row * DM + c] = acc[m][n][r] + bv;
            }
    }
}

// ---------------------------------------------------------------------------
extern "C" void kernel_launch(void* const* d_in, const int* in_sizes, int n_in,
                              void* d_out, int out_size, void* d_ws, size_t ws_size,
                              hipStream_t stream) {
    const float* x    = (const float*)d_in[0];
    const float* Wqkv = (const float*)d_in[1];
    const float* bqkv = (const float*)d_in[2];
    const float* Wout = (const float*)d_in[3];
    const float* bout = (const float*)d_in[4];
    const float* relb = (const float*)d_in[5];
    float* out = (float*)d_out;

    u16* ws    = (u16*)d_ws;
    u16* xb    = ws;                       // 4096*1024
    u16* WqkvT = xb + 4194304;             // 3072*1024
    u16* WoutT = WqkvT + 3145728;          // 1024*1024
    u16* qkpl  = WoutT + 1048576;          // [2][B][H][S][D] = 8388608
    u16* Vt    = qkpl + 8388608;           // [B][H][D][S]    = 4194304
    u16* aout  = Vt + 4194304;             // 4096*1024       = 4194304
    float* relb2 = (float*)(aout + 4194304); // 4095 floats

    relattn_prep<<<3076, 256, 0, stream>>>(x, Wqkv, Wout, relb, xb, WqkvT, WoutT, relb2);
    relattn_gemm_qkv<<<dim3(24, 32), 256, 0, stream>>>(xb, WqkvT, bqkv, qkpl, Vt);
    relattn_attn<<<dim3(16, 32), 256, 0, stream>>>(qkpl, Vt, relb2, aout);
    relattn_gemm_out<<<dim3(8, 32), 256, 0, stream>>>(aout, WoutT, bout, out);
}

// Round 5
// 138.572 us; speedup vs baseline: 8.8071x; 1.0561x over previous
//
#include <hip/hip_runtime.h>
#include <cmath>

#define B_ 2
#define S_ 2048
#define H_ 16
#define D_ 64
#define DM 1024

typedef unsigned short u16;
using short8 = __attribute__((ext_vector_type(8))) short;
using f32x4  = __attribute__((ext_vector_type(4))) float;
using f32x16 = __attribute__((ext_vector_type(16))) float;
using i32x4  = __attribute__((ext_vector_type(4))) int;

__device__ __forceinline__ u16 f32_to_bf16(float f) {
    unsigned int u = __float_as_uint(f);
    u += 0x7fffu + ((u >> 16) & 1u);   // round-to-nearest-even
    return (u16)(u >> 16);
}

__device__ __forceinline__ float exp2_fast(float x) {
    float r;
    asm("v_exp_f32 %0, %1" : "=v"(r) : "v"(x));
    return r;
}

__device__ __forceinline__ int cvt_pk_bf16(float lo, float hi) {
    int r;
    asm("v_cvt_pk_bf16_f32 %0, %1, %2" : "=v"(r) : "v"(lo), "v"(hi));
    return r;
}

__device__ __forceinline__ void gl_lds16(const void* src, void* dst) {
    __builtin_amdgcn_global_load_lds(
        (const __attribute__((address_space(1))) unsigned int*)src,
        (__attribute__((address_space(3))) unsigned int*)dst, 16, 0, 0);
}

__device__ __forceinline__ f32x16 mfma32(short8 a, short8 b, f32x16 c) {
    return __builtin_amdgcn_mfma_f32_32x32x16_bf16(a, b, c, 0, 0, 0);
}

// ---------------------------------------------------------------------------
// prep: x -> bf16 ; Wqkv -> bf16 T [3072][1024]; Wout -> bf16 T [1024][1024];
//       relb -> relb2 = relb * log2(e)
// ---------------------------------------------------------------------------
__global__ __launch_bounds__(256) void relattn_prep(
    const float* __restrict__ x, const float* __restrict__ Wqkv,
    const float* __restrict__ Wout, const float* __restrict__ relb,
    u16* __restrict__ xb, u16* __restrict__ WqkvT, u16* __restrict__ WoutT,
    float* __restrict__ relb2)
{
    __shared__ float T[64][65];
    const int tid = threadIdx.x;
    int blk = blockIdx.x;
    if (blk >= 3072) {                      // scale bias table into log2 domain
        int i0 = ((blk - 3072) * 256 + tid) * 4;
#pragma unroll
        for (int j = 0; j < 4; ++j)
            if (i0 + j < 2 * 2048 - 1)
                relb2[i0 + j] = relb[i0 + j] * 1.44269504f;
        return;
    }
    if (blk < 2048) {                       // convert x: 8 elems/thread
        size_t base = ((size_t)blk * 256 + tid) * 8;
        float4 v0 = *(const float4*)(x + base);
        float4 v1 = *(const float4*)(x + base + 4);
        ushort4 p0 = make_ushort4(f32_to_bf16(v0.x), f32_to_bf16(v0.y),
                                  f32_to_bf16(v0.z), f32_to_bf16(v0.w));
        ushort4 p1 = make_ushort4(f32_to_bf16(v1.x), f32_to_bf16(v1.y),
                                  f32_to_bf16(v1.z), f32_to_bf16(v1.w));
        *(ushort4*)(xb + base) = p0;
        *(ushort4*)(xb + base + 4) = p1;
        return;
    }
    int id = blk - 2048;
    const float* in; u16* outp; int R, C;
    if (id < 768) { in = Wqkv; outp = WqkvT; R = 1024; C = 3072; }
    else          { id -= 768; in = Wout;  outp = WoutT; R = 1024; C = 1024; }
    const int tpr = C >> 6;
    const int r0 = (id / tpr) << 6, c0 = (id % tpr) << 6;
#pragma unroll
    for (int it = 0; it < 4; ++it) {
        int e = tid + it * 256;
        int row = e >> 4, c4 = (e & 15) << 2;
        float4 v = *(const float4*)(in + (size_t)(r0 + row) * C + c0 + c4);
        T[row][c4 + 0] = v.x; T[row][c4 + 1] = v.y;
        T[row][c4 + 2] = v.z; T[row][c4 + 3] = v.w;
    }
    __syncthreads();
#pragma unroll
    for (int it = 0; it < 4; ++it) {
        int e = tid + it * 256;
        int crow = e >> 4, r4 = (e & 15) << 2;
        ushort4 pk = make_ushort4(f32_to_bf16(T[r4 + 0][crow]), f32_to_bf16(T[r4 + 1][crow]),
                                  f32_to_bf16(T[r4 + 2][crow]), f32_to_bf16(T[r4 + 3][crow]));
        *(ushort4*)(outp + (size_t)(c0 + crow) * R + r0 + r4) = pk;
    }
}

// ---------------------------------------------------------------------------
// GEMM1: xb @ WqkvT^T + bqkv -> q,k planes [2][B][H][S][D]; v -> Vt [B][H][D][S]
// ---------------------------------------------------------------------------
__global__ __launch_bounds__(256) void relattn_gemm_qkv(
    const u16* __restrict__ A, const u16* __restrict__ Bm,
    const float* __restrict__ bias, u16* __restrict__ qk, u16* __restrict__ Vt)
{
    __shared__ alignas(16) unsigned char AsB[16384];
    __shared__ alignas(16) unsigned char BsB[16384];
    const int tid = threadIdx.x;
    const int w = tid >> 6, l = tid & 63, ln = l & 15, hi = l >> 4;
    const int wr = w >> 1, wc = w & 1;
    const int row0 = blockIdx.y * 128, col0 = blockIdx.x * 128;
    const char* Ab = (const char*)A;
    const char* Bb = (const char*)Bm;

    f32x4 acc[4][4] = {};
    for (int step = 0; step < 16; ++step) {
        __syncthreads();
#pragma unroll
        for (int it = 0; it < 4; ++it) {
            int dsto = it * 4096 + w * 1024;
            int o = dsto + l * 16;
            int row = o >> 7;
            int swz = (o & 127) ^ ((row & 7) << 4);
            gl_lds16(Ab + (size_t)(row0 + row) * 2048 + step * 128 + swz, AsB + dsto);
            gl_lds16(Bb + (size_t)(col0 + row) * 2048 + step * 128 + swz, BsB + dsto);
        }
        __syncthreads();
#pragma unroll
        for (int kk = 0; kk < 2; ++kk) {
            short8 a[4], b[4];
            const int kb = hi * 16 + kk * 64;
#pragma unroll
            for (int m = 0; m < 4; ++m) {
                int row = wr * 64 + m * 16 + ln;
                a[m] = *(const short8*)(AsB + row * 128 + (kb ^ ((row & 7) << 4)));
            }
#pragma unroll
            for (int n = 0; n < 4; ++n) {
                int row = wc * 64 + n * 16 + ln;
                b[n] = *(const short8*)(BsB + row * 128 + (kb ^ ((row & 7) << 4)));
            }
#pragma unroll
            for (int m = 0; m < 4; ++m)
#pragma unroll
                for (int n = 0; n < 4; ++n)
                    acc[m][n] = __builtin_amdgcn_mfma_f32_16x16x32_bf16(a[m], b[n], acc[m][n], 0, 0, 0);
        }
    }

    const int t = col0 >> 10;
    const int bb = row0 >> 11;
    if (t < 2) {
#pragma unroll
        for (int n = 0; n < 4; ++n) {
            int c = col0 + wc * 64 + n * 16 + ln;
            int h = (c >> 6) & 15, d = c & 63;
            float bv = bias[c];
            u16* plane = qk + (size_t)((t * B_ + bb) * H_ + h) * S_ * D_;
#pragma unroll
            for (int m = 0; m < 4; ++m)
#pragma unroll
                for (int r = 0; r < 4; ++r) {
                    int s = (row0 + wr * 64 + m * 16 + hi * 4 + r) & (S_ - 1);
                    plane[(size_t)s * D_ + d] = f32_to_bf16(acc[m][n][r] + bv);
                }
        }
    } else {
#pragma unroll
        for (int n = 0; n < 4; ++n) {
            int c = col0 + wc * 64 + n * 16 + ln;
            int h = (c >> 6) & 15, d = c & 63;
            float bv = bias[c];
            u16* vrow = Vt + (size_t)((bb * H_ + h) * D_ + d) * S_;
#pragma unroll
            for (int m = 0; m < 4; ++m) {
                int s = (row0 + wr * 64 + m * 16 + hi * 4) & (S_ - 1);
                ushort4 pk = make_ushort4(f32_to_bf16(acc[m][n][0] + bv),
                                          f32_to_bf16(acc[m][n][1] + bv),
                                          f32_to_bf16(acc[m][n][2] + bv),
                                          f32_to_bf16(acc[m][n][3] + bv));
                *(ushort4*)(vrow + s) = pk;
            }
        }
    }
}

// ---------------------------------------------------------------------------
// Flash attention, fully swapped: S^T = K Q^T, O^T = V^T P^T.
// 8 waves x 512 threads. Waves 0-3: kv [0,1024); waves 4-7: kv [1024,2048),
// same 128 q-rows. Each group has its own K/V double-buffer (64KB LDS).
// Lane-aligned online-softmax merge of the two kv-halves through LDS.
// ---------------------------------------------------------------------------
__global__ __launch_bounds__(512, 4) void relattn_attn(
    const u16* __restrict__ qk, const u16* __restrict__ Vt,
    const float* __restrict__ relb2, u16* __restrict__ aout)
{
    __shared__ alignas(16) unsigned char Lds[65536];  // [group][buf][K 8K | V 8K]
    const int tid = threadIdx.x;
    const int w = tid >> 6, l = tid & 63;
    const int wg = w & 3, g = w >> 2;
    const int l31 = l & 31, h2 = l >> 5;
    const int qt = blockIdx.x, bh = blockIdx.y;
    const int bb = bh >> 4;
    const char* qpl = (const char*)(qk + (size_t)bh * (S_ * D_));
    const char* kpl = (const char*)(qk + (size_t)(B_ * H_ + bh) * (S_ * D_));
    const char* vpl = (const char*)(Vt + (size_t)bh * (D_ * S_));
    unsigned char* GB = Lds + g * 32768;

    const int q0 = qt * 128 + wg * 32;
    const int qrow = q0 + l31;
    const int kvbase = g * 1024;

    // Q fragments: B-operand of swapped QK^T; lane: row qrow, k-half h2
    short8 qf[4];
#pragma unroll
    for (int kd = 0; kd < 4; ++kd)
        qf[kd] = *(const short8*)(qpl + (size_t)qrow * 128 + kd * 32 + h2 * 16);

    f32x16 O0 = {}, O1 = {};
    float mrun = -1e30f, lrun = 0.f;

    // ---- prologue: stage this group's kt=0 into buf 0
    {
#pragma unroll
        for (int it = 0; it < 2; ++it) {
            int dsto = it * 4096 + wg * 1024;
            int o = dsto + l * 16;
            int row = o >> 7;
            int swz = (o & 127) ^ ((row & 7) << 4);
            gl_lds16(kpl + (size_t)(kvbase + row) * 128 + swz, GB + dsto);
            gl_lds16(vpl + (size_t)row * (S_ * 2) + kvbase * 2 + swz, GB + 8192 + dsto);
        }
    }
    __syncthreads();

    for (int kt = 0; kt < 16; ++kt) {
        const int buf = kt & 1;
        const unsigned char* KB = GB + buf * 16384;
        const unsigned char* VB = KB + 8192;
        const int kv0 = kvbase + kt * 64;

        // ---- prefetch next tile into other buffer
        if (kt < 15) {
#pragma unroll
            for (int it = 0; it < 2; ++it) {
                int dsto = it * 4096 + wg * 1024;
                int o = dsto + l * 16;
                int row = o >> 7;
                int swz = (o & 127) ^ ((row & 7) << 4);
                unsigned char* db = GB + (buf ^ 1) * 16384 + dsto;
                gl_lds16(kpl + (size_t)(kv0 + 64 + row) * 128 + swz, db);
                gl_lds16(vpl + (size_t)row * (S_ * 2) + (kv0 + 64) * 2 + swz, db + 8192);
            }
        }

        // ---- S^T = K Q^T : lane owns q-col qrow; regs span kv0..kv0+63
        f32x16 s0 = {}, s1 = {};
#pragma unroll
        for (int kd = 0; kd < 4; ++kd) {
            int kbyte = kd * 32 + h2 * 16;
            int sw = (l31 & 7) << 4;
            short8 k0 = *(const short8*)(KB + l31 * 128 + (kbyte ^ sw));
            short8 k1 = *(const short8*)(KB + (32 + l31) * 128 + (kbyte ^ sw));
            s0 = mfma32(k0, qf[kd], s0);
            s1 = mfma32(k1, qf[kd], s1);
        }

        // ---- scale + relative bias (log2 domain)
        const float SC2 = 0.125f * 1.44269504f;
        const float* bp = relb2 + (qrow - kv0 - 4 * h2 + 2047);
#pragma unroll
        for (int rq = 0; rq < 4; ++rq)
#pragma unroll
            for (int j = 0; j < 4; ++j) {
                s0[rq * 4 + j] = s0[rq * 4 + j] * SC2 + bp[-(8 * rq + j)];
                s1[rq * 4 + j] = s1[rq * 4 + j] * SC2 + bp[-(32 + 8 * rq + j)];
            }

        // ---- online softmax, in-lane + one cross-half combine
        float tm = -1e30f;
#pragma unroll
        for (int r = 0; r < 16; ++r) {
            tm = fmaxf(tm, s0[r]);
            tm = fmaxf(tm, s1[r]);
        }
        tm = fmaxf(tm, __shfl_xor(tm, 32));
        float nm = fmaxf(mrun, tm);
        float al = exp2_fast(mrun - nm);
        mrun = nm;
        float ps = 0.f;
#pragma unroll
        for (int r = 0; r < 16; ++r) { s0[r] = exp2_fast(s0[r] - nm); ps += s0[r]; }
#pragma unroll
        for (int r = 0; r < 16; ++r) { s1[r] = exp2_fast(s1[r] - nm); ps += s1[r]; }
        ps += __shfl_xor(ps, 32);
        lrun = lrun * al + ps;
#pragma unroll
        for (int r = 0; r < 16; ++r) { O0[r] *= al; O1[r] *= al; }

        // ---- P -> B-fragments (half-exchange) + swapped PV: O^T = V^T P^T
#pragma unroll
        for (int ts = 0; ts < 4; ++ts) {
            float p0, p1, p2, p3, p4, p5, p6, p7;
            if (ts == 0)      { p0=s0[0];  p1=s0[1];  p2=s0[2];  p3=s0[3];  p4=s0[4];  p5=s0[5];  p6=s0[6];  p7=s0[7]; }
            else if (ts == 1) { p0=s0[8];  p1=s0[9];  p2=s0[10]; p3=s0[11]; p4=s0[12]; p5=s0[13]; p6=s0[14]; p7=s0[15]; }
            else if (ts == 2) { p0=s1[0];  p1=s1[1];  p2=s1[2];  p3=s1[3];  p4=s1[4];  p5=s1[5];  p6=s1[6];  p7=s1[7]; }
            else              { p0=s1[8];  p1=s1[9];  p2=s1[10]; p3=s1[11]; p4=s1[12]; p5=s1[13]; p6=s1[14]; p7=s1[15]; }
            int c01 = cvt_pk_bf16(p0, p1), c23 = cvt_pk_bf16(p2, p3);
            int c45 = cvt_pk_bf16(p4, p5), c67 = cvt_pk_bf16(p6, p7);
            int px01 = __shfl_xor(c01, 32), px23 = __shfl_xor(c23, 32);
            int px45 = __shfl_xor(c45, 32), px67 = __shfl_xor(c67, 32);
            i32x4 pw;
            pw[0] = h2 ? px45 : c01;
            pw[1] = h2 ? px67 : c23;
            pw[2] = h2 ? c45 : px01;
            pw[3] = h2 ? c67 : px23;
            short8 pb = __builtin_bit_cast(short8, pw);
            int vbyte = ts * 32 + h2 * 16;
            int sw = (l31 & 7) << 4;
            short8 v0 = *(const short8*)(VB + l31 * 128 + (vbyte ^ sw));
            short8 v1 = *(const short8*)(VB + (32 + l31) * 128 + (vbyte ^ sw));
            O0 = mfma32(v0, pb, O0);   // D[d][q]: col = q = l31 -> alpha in-lane
            O1 = mfma32(v1, pb, O1);
        }
        __syncthreads();   // drains vmcnt (prefetch) + lgkm; next buf ready
    }

    // ---- merge the two kv-half partials (lane-aligned across wave pair)
    // pair region (wg): O 8192B + m 256B + l 256B = 8704B
    {
        float* PO = (float*)(Lds + wg * 8704);
        float* PM = (float*)(Lds + wg * 8704 + 8192);
        float* PL = (float*)(Lds + wg * 8704 + 8448);
        if (g == 1) {
#pragma unroll
            for (int r = 0; r < 16; ++r) {
                PO[l * 32 + r] = O0[r];
                PO[l * 32 + 16 + r] = O1[r];
            }
            PM[l] = mrun;
            PL[l] = lrun;
        }
        __syncthreads();
        if (g == 1) return;
        float m1v = PM[l], l1v = PL[l];
        float nm = fmaxf(mrun, m1v);
        float a0 = exp2_fast(mrun - nm), a1 = exp2_fast(m1v - nm);
        float lr = lrun * a0 + l1v * a1;
        float inv = 1.0f / lr;
        const float* src = PO + l * 32;
        u16* orow = aout + (size_t)(bb * S_ + qrow) * DM + (bh & 15) * 64 + 4 * h2;
#pragma unroll
        for (int gq = 0; gq < 4; ++gq) {
            ushort4 w0, w1;
            float o00 = (O0[4*gq+0] * a0 + src[4*gq+0] * a1) * inv;
            float o01 = (O0[4*gq+1] * a0 + src[4*gq+1] * a1) * inv;
            float o02 = (O0[4*gq+2] * a0 + src[4*gq+2] * a1) * inv;
            float o03 = (O0[4*gq+3] * a0 + src[4*gq+3] * a1) * inv;
            float o10 = (O1[4*gq+0] * a0 + src[16+4*gq+0] * a1) * inv;
            float o11 = (O1[4*gq+1] * a0 + src[16+4*gq+1] * a1) * inv;
            float o12 = (O1[4*gq+2] * a0 + src[16+4*gq+2] * a1) * inv;
            float o13 = (O1[4*gq+3] * a0 + src[16+4*gq+3] * a1) * inv;
            w0 = make_ushort4(f32_to_bf16(o00), f32_to_bf16(o01), f32_to_bf16(o02), f32_to_bf16(o03));
            w1 = make_ushort4(f32_to_bf16(o10), f32_to_bf16(o11), f32_to_bf16(o12), f32_to_bf16(o13));
            *(ushort4*)(orow + 8 * gq) = w0;
            *(ushort4*)(orow + 32 + 8 * gq) = w1;
        }
    }
}

// ---------------------------------------------------------------------------
// GEMM2: aout[4096,1024](bf16) @ WoutT[1024,1024]^T + bout -> out f32
// ---------------------------------------------------------------------------
__global__ __launch_bounds__(256) void relattn_gemm_out(
    const u16* __restrict__ A, const u16* __restrict__ Bm,
    const float* __restrict__ bias, float* __restrict__ out)
{
    __shared__ alignas(16) unsigned char AsB[16384];
    __shared__ alignas(16) unsigned char BsB[16384];
    const int tid = threadIdx.x;
    const int w = tid >> 6, l = tid & 63, ln = l & 15, hi = l >> 4;
    const int wr = w >> 1, wc = w & 1;
    const int row0 = blockIdx.y * 128, col0 = blockIdx.x * 128;
    const char* Ab = (const char*)A;
    const char* Bb = (const char*)Bm;

    f32x4 acc[4][4] = {};
    for (int step = 0; step < 16; ++step) {
        __syncthreads();
#pragma unroll
        for (int it = 0; it < 4; ++it) {
            int dsto = it * 4096 + w * 1024;
            int o = dsto + l * 16;
            int row = o >> 7;
            int swz = (o & 127) ^ ((row & 7) << 4);
            gl_lds16(Ab + (size_t)(row0 + row) * 2048 + step * 128 + swz, AsB + dsto);
            gl_lds16(Bb + (size_t)(col0 + row) * 2048 + step * 128 + swz, BsB + dsto);
        }
        __syncthreads();
#pragma unroll
        for (int kk = 0; kk < 2; ++kk) {
            short8 a[4], b[4];
            const int kb = hi * 16 + kk * 64;
#pragma unroll
            for (int m = 0; m < 4; ++m) {
                int row = wr * 64 + m * 16 + ln;
                a[m] = *(const short8*)(AsB + row * 128 + (kb ^ ((row & 7) << 4)));
            }
#pragma unroll
            for (int n = 0; n < 4; ++n) {
                int row = wc * 64 + n * 16 + ln;
                b[n] = *(const short8*)(BsB + row * 128 + (kb ^ ((row & 7) << 4)));
            }
#pragma unroll
            for (int m = 0; m < 4; ++m)
#pragma unroll
                for (int n = 0; n < 4; ++n)
                    acc[m][n] = __builtin_amdgcn_mfma_f32_16x16x32_bf16(a[m], b[n], acc[m][n], 0, 0, 0);
        }
    }

#pragma unroll
    for (int n = 0; n < 4; ++n) {
        int c = col0 + wc * 64 + n * 16 + ln;
        float bv = bias[c];
#pragma unroll
        for (int m = 0; m < 4; ++m)
#pragma unroll
            for (int r = 0; r < 4; ++r) {
                int row = row0 + wr * 64 + m * 16 + hi * 4 + r;
                out[(size_t)row * DM + c] = acc[m][n][r] + bv;
            }
    }
}

// ---------------------------------------------------------------------------
extern "C" void kernel_launch(void* const* d_in, const int* in_sizes, int n_in,
                              void* d_out, int out_size, void* d_ws, size_t ws_size,
                              hipStream_t stream) {
    const float* x    = (const float*)d_in[0];
    const float* Wqkv = (const float*)d_in[1];
    const float* bqkv = (const float*)d_in[2];
    const float* Wout = (const float*)d_in[3];
    const float* bout = (const float*)d_in[4];
    const float* relb = (const float*)d_in[5];
    float* out = (float*)d_out;

    u16* ws    = (u16*)d_ws;
    u16* xb    = ws;                       // 4096*1024
    u16* WqkvT = xb + 4194304;             // 3072*1024
    u16* WoutT = WqkvT + 3145728;          // 1024*1024
    u16* qkpl  = WoutT + 1048576;          // [2][B][H][S][D] = 8388608
    u16* Vt    = qkpl + 8388608;           // [B][H][D][S]    = 4194304
    u16* aout  = Vt + 4194304;             // 4096*1024       = 4194304
    float* relb2 = (float*)(aout + 4194304); // 4095 floats

    relattn_prep<<<3076, 256, 0, stream>>>(x, Wqkv, Wout, relb, xb, WqkvT, WoutT, relb2);
    relattn_gemm_qkv<<<dim3(24, 32), 256, 0, stream>>>(xb, WqkvT, bqkv, qkpl, Vt);
    relattn_attn<<<dim3(16, 32), 512, 0, stream>>>(qkpl, Vt, relb2, aout);
    relattn_gemm_out<<<dim3(8, 32), 256, 0, stream>>>(aout, WoutT, bout, out);
}